// Round 5
// baseline (561.221 us; speedup 1.0000x reference)
//
#include <hip/hip_runtime.h>
#include <hip/hip_bf16.h>
#include <math.h>

#define N_SEQ  2048
#define DMODEL 2048
#define NHEAD  16
#define HDIM   128
#define QKV_LD 6144   // 3*DMODEL

typedef __attribute__((ext_vector_type(8))) short bf16x8;
typedef __attribute__((ext_vector_type(4))) float f32x4;

__device__ __forceinline__ ushort f2bf(float x) {
    union { float f; unsigned u; } v; v.f = x;
    unsigned r = (v.u + 0x7fffu + ((v.u >> 16) & 1u)) >> 16;
    return (ushort)r;
}
__device__ __forceinline__ float bf2f(ushort h) {
    union { unsigned u; float f; } v; v.u = ((unsigned)h) << 16;
    return v.f;
}

// ===========================================================================
// convert_split: fp32 [n] -> bf16 hi/lo same layout (vectorized float4)
// ===========================================================================
__global__ __launch_bounds__(256)
void convert_split(const float* __restrict__ in, ushort* __restrict__ oh,
                   ushort* __restrict__ ol, int n4)
{
    int i = blockIdx.x * 256 + threadIdx.x;
    if (i >= n4) return;
    float4 v = ((const float4*)in)[i];
    ushort4 h, l;
    h.x = f2bf(v.x); l.x = f2bf(v.x - bf2f(h.x));
    h.y = f2bf(v.y); l.y = f2bf(v.y - bf2f(h.y));
    h.z = f2bf(v.z); l.z = f2bf(v.z - bf2f(h.z));
    h.w = f2bf(v.w); l.w = f2bf(v.w - bf2f(h.w));
    ((ushort4*)oh)[i] = h;
    ((ushort4*)ol)[i] = l;
}

// ===========================================================================
// convert_split_t: fp32 [R][C] -> bf16 hi/lo transposed [C][R]
// ===========================================================================
__global__ __launch_bounds__(256)
void convert_split_t(const float* __restrict__ in, ushort* __restrict__ oh,
                     ushort* __restrict__ ol, int R, int C)
{
    __shared__ float T[64][65];
    const int t = threadIdx.x;
    const int c0 = blockIdx.x * 64, r0 = blockIdx.y * 64;
    #pragma unroll
    for (int p = 0; p < 4; ++p) {
        int r = (t >> 4) + p * 16;
        int c4 = (t & 15) * 4;
        float4 v = *(const float4*)&in[(size_t)(r0 + r) * C + c0 + c4];
        T[r][c4] = v.x; T[r][c4 + 1] = v.y; T[r][c4 + 2] = v.z; T[r][c4 + 3] = v.w;
    }
    __syncthreads();
    #pragma unroll
    for (int p = 0; p < 4; ++p) {
        int c = (t >> 4) + p * 16;
        int r4 = (t & 15) * 4;
        float f0 = T[r4][c], f1 = T[r4 + 1][c], f2 = T[r4 + 2][c], f3 = T[r4 + 3][c];
        ushort4 h, l;
        h.x = f2bf(f0); l.x = f2bf(f0 - bf2f(h.x));
        h.y = f2bf(f1); l.y = f2bf(f1 - bf2f(h.y));
        h.z = f2bf(f2); l.z = f2bf(f2 - bf2f(h.z));
        h.w = f2bf(f3); l.w = f2bf(f3 - bf2f(h.w));
        *(ushort4*)&oh[(size_t)(c0 + c) * R + r0 + r4] = h;
        *(ushort4*)&ol[(size_t)(c0 + c) * R + r0 + r4] = l;
    }
}

// ===========================================================================
// transpose_v: qkv_hi [2048][6144] cols 4096.. (= V bf16) -> vt [2048][2048]
// ===========================================================================
__global__ __launch_bounds__(256)
void transpose_v(const ushort* __restrict__ qkvh, ushort* __restrict__ vt)
{
    __shared__ ushort T[64][72];
    const int t = threadIdx.x;
    const int c0 = blockIdx.x * 64, n0 = blockIdx.y * 64;
    #pragma unroll
    for (int p = 0; p < 2; ++p) {
        int r = (t >> 3) + p * 32;
        int u = (t & 7) * 8;
        *(bf16x8*)&T[r][u] = *(const bf16x8*)&qkvh[(size_t)(n0 + r) * QKV_LD + 2 * DMODEL + c0 + u];
    }
    __syncthreads();
    #pragma unroll
    for (int p = 0; p < 2; ++p) {
        int d = (t >> 3) + p * 32;
        int ju = (t & 7) * 8;
        bf16x8 o;
        #pragma unroll
        for (int i = 0; i < 8; ++i) o[i] = (short)T[ju + i][d];
        *(bf16x8*)&vt[(size_t)(c0 + d) * N_SEQ + n0 + ju] = o;
    }
}

// ===========================================================================
// gemm_bf16x3_v3: 128x128 tile, BK=32, 256 thr (4 waves 2x2 of 64x64).
// v1's grid fill (2 blocks/CU) + v2's pitch-68 conflict-free LDS + v2's
// single-raw-barrier register double-buffer schedule.
// Row layout in LDS: [hi 32 | lo 32 | pad 4] ushorts, pitch 68 (136 B).
// ===========================================================================
template<bool BF16OUT>
__global__ __launch_bounds__(256, 2)
void gemm_bf16x3_v3(const ushort* __restrict__ Ah_g, const ushort* __restrict__ Al_g,
                    const ushort* __restrict__ Bh_g, const ushort* __restrict__ Bl_g,
                    ushort* __restrict__ Ch, ushort* __restrict__ Cl,
                    float* __restrict__ Cf, int M, int N, int K)
{
    __shared__ ushort bufA[2][128 * 68];
    __shared__ ushort bufB[2][128 * 68];

    const int t = threadIdx.x;
    const int l = t & 63, w = t >> 6;
    const int l15 = l & 15, kgr = l >> 4;
    const int wm = (w >> 1) * 64, wn = (w & 1) * 64;

    // XCD-aware bijective swizzle (nwg % 8 == 0 for all our launches)
    const int nbx = N / 128;
    const int nwg = nbx * (M / 128);
    int flat = blockIdx.x + blockIdx.y * nbx;
    if ((nwg & 7) == 0) flat = (flat & 7) * (nwg >> 3) + (flat >> 3);
    const int bm = (flat / nbx) * 128;
    const int bn = (flat % nbx) * 128;

    const int rA = t >> 1;             // 0..127 (tile row)
    const int hA = t & 1;              // 0=hi, 1=lo
    const ushort* gA = (hA ? Al_g : Ah_g) + (size_t)(bm + rA) * K;
    const ushort* gB = (hA ? Bl_g : Bh_g) + (size_t)(bn + rA) * K;

    bf16x8 stA[4], stB[4];
    auto load_regs = [&](int k0) {
        #pragma unroll
        for (int j = 0; j < 4; ++j) {
            stA[j] = *(const bf16x8*)(gA + k0 + j * 8);
            stB[j] = *(const bf16x8*)(gB + k0 + j * 8);
        }
    };
    auto write_lds = [&](int bsel) {
        #pragma unroll
        for (int j = 0; j < 4; ++j) {
            *(bf16x8*)&bufA[bsel][rA * 68 + hA * 32 + j * 8] = stA[j];
            *(bf16x8*)&bufB[bsel][rA * 68 + hA * 32 + j * 8] = stB[j];
        }
    };

    f32x4 acc[4][4] = {};
    const int nt = K / 32;
    load_regs(0);
    write_lds(0);
    load_regs(32);

    for (int i = 0; i < nt; ++i) {
        const int c = i & 1;
        // raw barrier: drains LDS ops only; global loads issued last iter
        // stay in flight (vmcnt waits auto-inserted at their reg use below).
        asm volatile("s_waitcnt lgkmcnt(0)\n\ts_barrier" ::: "memory");
        if (i + 1 < nt) write_lds(c ^ 1);
        if (i + 2 < nt) load_regs((i + 2) * 32);

        bf16x8 bh[4], bl[4];
        #pragma unroll
        for (int nf = 0; nf < 4; ++nf) {
            const int r = wn + nf * 16 + l15;
            bh[nf] = *(const bf16x8*)&bufB[c][r * 68 + kgr * 8];
            bl[nf] = *(const bf16x8*)&bufB[c][r * 68 + 32 + kgr * 8];
        }
        #pragma unroll
        for (int mf = 0; mf < 4; ++mf) {
            const int r = wm + mf * 16 + l15;
            bf16x8 ah = *(const bf16x8*)&bufA[c][r * 68 + kgr * 8];
            bf16x8 al = *(const bf16x8*)&bufA[c][r * 68 + 32 + kgr * 8];
            #pragma unroll
            for (int nf = 0; nf < 4; ++nf) {
                acc[mf][nf] = __builtin_amdgcn_mfma_f32_16x16x32_bf16(ah, bh[nf], acc[mf][nf], 0, 0, 0);
                acc[mf][nf] = __builtin_amdgcn_mfma_f32_16x16x32_bf16(ah, bl[nf], acc[mf][nf], 0, 0, 0);
                acc[mf][nf] = __builtin_amdgcn_mfma_f32_16x16x32_bf16(al, bh[nf], acc[mf][nf], 0, 0, 0);
            }
        }
    }

    #pragma unroll
    for (int mf = 0; mf < 4; ++mf)
        #pragma unroll
        for (int nf = 0; nf < 4; ++nf)
            #pragma unroll
            for (int r = 0; r < 4; ++r) {
                const int m = bm + wm + mf * 16 + kgr * 4 + r;
                const int n = bn + wn + nf * 16 + l15;
                const float v = acc[mf][nf][r];
                if constexpr (BF16OUT) {
                    ushort h = f2bf(v);
                    Ch[(size_t)m * N + n] = h;
                    Cl[(size_t)m * N + n] = f2bf(v - bf2f(h));
                } else {
                    Cf[(size_t)m * N + n] = v;
                }
            }
}

// ===========================================================================
// attn_mfma2: diagonal-paired flash attention.
// grid (16, 16) = 256 blocks (1/CU, exact fill), 256 thr (4 waves).
// Block b owns q-strips b and 31-b (64 rows each). Wave w: frag0 = rows
// b*64+w*16.., frag1 = rows (31-b)*64+w*16.. -> every wave computes exactly
// 33 frag-tiles (perfect causal balance). K hi/lo + V^T double-buffered in
// LDS (single raw barrier per tile); 32 shared K-reads feed 96 MFMAs.
// Softmax in-register per frag (16-lane butterfly); P -> per-wave St LDS.
// ===========================================================================
__global__ __launch_bounds__(256)
void attn_mfma2(const ushort* __restrict__ qkvh, const ushort* __restrict__ qkvl,
                const ushort* __restrict__ vt,
                ushort* __restrict__ oh, ushort* __restrict__ ol)
{
    __shared__ ushort Kh[2][64 * 136], Kl[2][64 * 136];
    __shared__ ushort Vts[2][128 * 68];
    __shared__ ushort St[4][32 * 68];

    const int t = threadIdx.x;
    const int l = t & 63;
    const int w = t >> 6;
    const int l15 = l & 15, kgr = l >> 4;
    const int h = blockIdx.y, b = blockIdx.x;
    const int q00 = b * 64 + w * 16;          // frag0 rows (low strip)
    const int q01 = (31 - b) * 64 + w * 16;   // frag1 rows (high strip)
    const int ntiles = 32 - b;                // covers j <= max q of high strip

    // Q fragments in registers (hi/lo), 2 frags x 4 k-chunks
    bf16x8 qh[2][4], ql[2][4];
    #pragma unroll
    for (int f = 0; f < 2; ++f) {
        const size_t base = (size_t)((f ? q01 : q00) + l15) * QKV_LD + h * HDIM;
        #pragma unroll
        for (int kc = 0; kc < 4; ++kc) {
            qh[f][kc] = *(const bf16x8*)(qkvh + base + kc * 32 + kgr * 8);
            ql[f][kc] = *(const bf16x8*)(qkvl + base + kc * 32 + kgr * 8);
        }
    }

    f32x4 o[2][8] = {};
    float m_run[2][4], l_run[2][4];
    #pragma unroll
    for (int f = 0; f < 2; ++f)
        #pragma unroll
        for (int r = 0; r < 4; ++r) { m_run[f][r] = -1e30f; l_run[f][r] = 0.f; }

    bf16x8 sKh[4], sKl[4], sV[4];
    auto load_tile = [&](int jb) {
        #pragma unroll
        for (int i = 0; i < 4; ++i) {
            int r = (t >> 4) + i * 16;
            size_t g = (size_t)(jb + r) * QKV_LD + DMODEL + h * HDIM + (t & 15) * 8;
            sKh[i] = *(const bf16x8*)(qkvh + g);
            sKl[i] = *(const bf16x8*)(qkvl + g);
        }
        #pragma unroll
        for (int i = 0; i < 4; ++i) {
            int d = (t >> 3) + i * 32;
            sV[i] = *(const bf16x8*)(vt + (size_t)(h * HDIM + d) * N_SEQ + jb + (t & 7) * 8);
        }
    };
    auto write_tile = [&](int c) {
        #pragma unroll
        for (int i = 0; i < 4; ++i) {
            int r = (t >> 4) + i * 16;
            *(bf16x8*)&Kh[c][r * 136 + (t & 15) * 8] = sKh[i];
            *(bf16x8*)&Kl[c][r * 136 + (t & 15) * 8] = sKl[i];
        }
        #pragma unroll
        for (int i = 0; i < 4; ++i) {
            int d = (t >> 3) + i * 32;
            *(bf16x8*)&Vts[c][d * 68 + (t & 7) * 8] = sV[i];
        }
    };

    const float scale = 0.08838834764831845f;  // 1/sqrt(128)

    load_tile(0);
    write_tile(0);
    load_tile(64);

    for (int jt = 0; jt < ntiles; ++jt) {
        const int jb = jt * 64;
        const int c = jt & 1;
        // raw barrier: LDS drained; K/V global loads stay in flight.
        asm volatile("s_waitcnt lgkmcnt(0)\n\ts_barrier" ::: "memory");
        if (jt + 1 < ntiles) write_tile(c ^ 1);
        if (jt + 2 < ntiles) load_tile(jb + 128);

        const bool f0on = (jt <= b);   // frag0 (low strip) active this tile

        // ---- S = scale * Q K^T; K reads shared by both frags
        float sv[2][4][4];
        #pragma unroll
        for (int jf = 0; jf < 4; ++jf) {
            f32x4 sacc0 = {}, sacc1 = {};
            #pragma unroll
            for (int kc = 0; kc < 4; ++kc) {
                bf16x8 kh = *(const bf16x8*)&Kh[c][(jf * 16 + l15) * 136 + kc * 32 + kgr * 8];
                bf16x8 kl = *(const bf16x8*)&Kl[c][(jf * 16 + l15) * 136 + kc * 32 + kgr * 8];
                sacc1 = __builtin_amdgcn_mfma_f32_16x16x32_bf16(qh[1][kc], kh, sacc1, 0, 0, 0);
                sacc1 = __builtin_amdgcn_mfma_f32_16x16x32_bf16(qh[1][kc], kl, sacc1, 0, 0, 0);
                sacc1 = __builtin_amdgcn_mfma_f32_16x16x32_bf16(ql[1][kc], kh, sacc1, 0, 0, 0);
                if (f0on) {
                    sacc0 = __builtin_amdgcn_mfma_f32_16x16x32_bf16(qh[0][kc], kh, sacc0, 0, 0, 0);
                    sacc0 = __builtin_amdgcn_mfma_f32_16x16x32_bf16(qh[0][kc], kl, sacc0, 0, 0, 0);
                    sacc0 = __builtin_amdgcn_mfma_f32_16x16x32_bf16(ql[0][kc], kh, sacc0, 0, 0, 0);
                }
            }
            const int j = jb + jf * 16 + l15;
            #pragma unroll
            for (int r = 0; r < 4; ++r) {
                sv[1][jf][r] = (j > q01 + kgr * 4 + r) ? -1e30f : sacc1[r] * scale;
                if (f0on)
                    sv[0][jf][r] = (j > q00 + kgr * 4 + r) ? -1e30f : sacc0[r] * scale;
            }
        }

        // ---- online softmax per active frag; p fused into St write
        float corr[2][4];
        #pragma unroll
        for (int f = 0; f < 2; ++f) {
            if (f == 0 && !f0on) continue;   // wave-uniform
            #pragma unroll
            for (int r = 0; r < 4; ++r) {
                float tm = fmaxf(fmaxf(sv[f][0][r], sv[f][1][r]),
                                 fmaxf(sv[f][2][r], sv[f][3][r]));
                tm = fmaxf(tm, __shfl_xor(tm, 1));
                tm = fmaxf(tm, __shfl_xor(tm, 2));
                tm = fmaxf(tm, __shfl_xor(tm, 4));
                tm = fmaxf(tm, __shfl_xor(tm, 8));
                const float nm = fmaxf(m_run[f][r], tm);
                corr[f][r] = __expf(m_run[f][r] - nm);
                m_run[f][r] = nm;
                float rs = 0.f;
                const int row = f * 16 + kgr * 4 + r;
                #pragma unroll
                for (int jf = 0; jf < 4; ++jf) {
                    const float pv = __expf(sv[f][jf][r] - nm);
                    St[w][row * 68 + jf * 16 + l15] = f2bf(pv);
                    rs += pv;
                }
                rs += __shfl_xor(rs, 1);
                rs += __shfl_xor(rs, 2);
                rs += __shfl_xor(rs, 4);
                rs += __shfl_xor(rs, 8);
                l_run[f][r] = l_run[f][r] * corr[f][r] + rs;
            }
        }

        // ---- rescale O
        #pragma unroll
        for (int f = 0; f < 2; ++f) {
            if (f == 0 && !f0on) continue;
            #pragma unroll
            for (int df = 0; df < 8; ++df)
                #pragma unroll
                for (int r = 0; r < 4; ++r) o[f][df][r] *= corr[f][r];
        }

        // ---- P @ V; V reads shared by both frags
        #pragma unroll
        for (int jc = 0; jc < 2; ++jc) {
            bf16x8 pa1 = *(const bf16x8*)&St[w][(16 + l15) * 68 + jc * 32 + kgr * 8];
            bf16x8 pa0 = {};
            if (f0on) pa0 = *(const bf16x8*)&St[w][l15 * 68 + jc * 32 + kgr * 8];
            #pragma unroll
            for (int df = 0; df < 8; ++df) {
                bf16x8 vb = *(const bf16x8*)&Vts[c][(df * 16 + l15) * 68 + jc * 32 + kgr * 8];
                o[1][df] = __builtin_amdgcn_mfma_f32_16x16x32_bf16(pa1, vb, o[1][df], 0, 0, 0);
                if (f0on)
                    o[0][df] = __builtin_amdgcn_mfma_f32_16x16x32_bf16(pa0, vb, o[0][df], 0, 0, 0);
            }
        }
    }

    // ---- epilogue: O /= l, write attn hi/lo for both strips
    #pragma unroll
    for (int f = 0; f < 2; ++f)
        #pragma unroll
        for (int r = 0; r < 4; ++r) l_run[f][r] = 1.f / l_run[f][r];
    #pragma unroll
    for (int f = 0; f < 2; ++f) {
        const int q0 = f ? q01 : q00;
        #pragma unroll
        for (int df = 0; df < 8; ++df)
            #pragma unroll
            for (int r = 0; r < 4; ++r) {
                const float v = o[f][df][r] * l_run[f][r];
                const size_t a = (size_t)(q0 + kgr * 4 + r) * DMODEL + h * HDIM + df * 16 + l15;
                const ushort hh = f2bf(v);
                oh[a] = hh;
                ol[a] = f2bf(v - bf2f(hh));
            }
    }
}

// ===========================================================================
extern "C" void kernel_launch(void* const* d_in, const int* in_sizes, int n_in,
                              void* d_out, int out_size, void* d_ws, size_t ws_size,
                              hipStream_t stream)
{
    const float* x    = (const float*)d_in[0];
    const float* Wqkv = (const float*)d_in[1];
    const float* Wout = (const float*)d_in[2];
    float* outp = (float*)d_out;

    // ws layout (bytes):
    //  [0, 8M)       x_hi   -> later attn_hi
    //  [8M, 16M)     x_lo   -> later attn_lo
    //  [16M, 64M)    wqkvt hi/lo -> later woutt hi/lo + vt
    //  [64M, 112M)   qkv hi/lo
    const size_t O_XHI = 0;
    const size_t O_XLO = 8388608;
    const size_t O_WT  = 16777216;
    const size_t O_QKV = 67108864;

    char* ws = (char*)d_ws;
    ushort* x_hi   = (ushort*)(ws + O_XHI);
    ushort* x_lo   = (ushort*)(ws + O_XLO);
    ushort* wqt_hi = (ushort*)(ws + O_WT);
    ushort* wqt_lo = (ushort*)(ws + O_WT + 25165824);
    ushort* qkv_hi = (ushort*)(ws + O_QKV);
    ushort* qkv_lo = (ushort*)(ws + O_QKV + 25165824);
    // after GEMM1 these alias the (dead) wqkvt region:
    ushort* wot_hi = (ushort*)(ws + O_WT);
    ushort* wot_lo = (ushort*)(ws + O_WT + 8388608);
    ushort* vt     = (ushort*)(ws + O_WT + 16777216);
    // after GEMM1 these alias the (dead) x region:
    ushort* at_hi  = (ushort*)(ws + O_XHI);
    ushort* at_lo  = (ushort*)(ws + O_XLO);

    // 1. split x
    convert_split<<<dim3(N_SEQ * DMODEL / 4 / 256), 256, 0, stream>>>(
        x, x_hi, x_lo, N_SEQ * DMODEL / 4);
    // 2. split + transpose Wqkv -> [6144][2048]
    convert_split_t<<<dim3(QKV_LD / 64, DMODEL / 64), 256, 0, stream>>>(
        Wqkv, wqt_hi, wqt_lo, DMODEL, QKV_LD);
    // 3. qkv = x @ Wqkv  (bf16 hi/lo out)
    gemm_bf16x3_v3<true><<<dim3(QKV_LD / 128, N_SEQ / 128), 256, 0, stream>>>(
        x_hi, x_lo, wqt_hi, wqt_lo, qkv_hi, qkv_lo, nullptr,
        N_SEQ, QKV_LD, DMODEL);
    // 4. split + transpose Wout -> [2048][2048]  (into dead wqkvt region)
    convert_split_t<<<dim3(DMODEL / 64, DMODEL / 64), 256, 0, stream>>>(
        Wout, wot_hi, wot_lo, DMODEL, DMODEL);
    // 5. transpose V (bf16 hi only)
    transpose_v<<<dim3(DMODEL / 64, N_SEQ / 64), 256, 0, stream>>>(qkv_hi, vt);
    // 6. attention (diagonal-paired; writes attn hi/lo into dead x region)
    attn_mfma2<<<dim3(16, NHEAD), 256, 0, stream>>>(
        qkv_hi, qkv_lo, vt, at_hi, at_lo);
    // 7. out = attn @ Wout (fp32 out)
    gemm_bf16x3_v3<false><<<dim3(DMODEL / 128, N_SEQ / 128), 256, 0, stream>>>(
        at_hi, at_lo, wot_hi, wot_lo, nullptr, nullptr, outp,
        N_SEQ, DMODEL, DMODEL);
}

// Round 8
// 488.896 us; speedup vs baseline: 1.1479x; 1.1479x over previous
//
#include <hip/hip_runtime.h>
#include <hip/hip_bf16.h>
#include <math.h>

#define N_SEQ  2048
#define DMODEL 2048
#define NHEAD  16
#define HDIM   128
#define QKV_LD 6144   // 3*DMODEL

typedef __attribute__((ext_vector_type(8))) short bf16x8;
typedef __attribute__((ext_vector_type(4))) float f32x4;

__device__ __forceinline__ ushort f2bf(float x) {
    union { float f; unsigned u; } v; v.f = x;
    unsigned r = (v.u + 0x7fffu + ((v.u >> 16) & 1u)) >> 16;
    return (ushort)r;
}
__device__ __forceinline__ float bf2f(ushort h) {
    union { unsigned u; float f; } v; v.u = ((unsigned)h) << 16;
    return v.f;
}

// ===========================================================================
// convert_split: fp32 [n] -> bf16 hi/lo same layout (vectorized float4)
// ===========================================================================
__global__ __launch_bounds__(256)
void convert_split(const float* __restrict__ in, ushort* __restrict__ oh,
                   ushort* __restrict__ ol, int n4)
{
    int i = blockIdx.x * 256 + threadIdx.x;
    if (i >= n4) return;
    float4 v = ((const float4*)in)[i];
    ushort4 h, l;
    h.x = f2bf(v.x); l.x = f2bf(v.x - bf2f(h.x));
    h.y = f2bf(v.y); l.y = f2bf(v.y - bf2f(h.y));
    h.z = f2bf(v.z); l.z = f2bf(v.z - bf2f(h.z));
    h.w = f2bf(v.w); l.w = f2bf(v.w - bf2f(h.w));
    ((ushort4*)oh)[i] = h;
    ((ushort4*)ol)[i] = l;
}

// ===========================================================================
// convert_split_t: fp32 [R][C] -> bf16 hi/lo transposed [C][R]
// ===========================================================================
__global__ __launch_bounds__(256)
void convert_split_t(const float* __restrict__ in, ushort* __restrict__ oh,
                     ushort* __restrict__ ol, int R, int C)
{
    __shared__ float T[64][65];
    const int t = threadIdx.x;
    const int c0 = blockIdx.x * 64, r0 = blockIdx.y * 64;
    #pragma unroll
    for (int p = 0; p < 4; ++p) {
        int r = (t >> 4) + p * 16;
        int c4 = (t & 15) * 4;
        float4 v = *(const float4*)&in[(size_t)(r0 + r) * C + c0 + c4];
        T[r][c4] = v.x; T[r][c4 + 1] = v.y; T[r][c4 + 2] = v.z; T[r][c4 + 3] = v.w;
    }
    __syncthreads();
    #pragma unroll
    for (int p = 0; p < 4; ++p) {
        int c = (t >> 4) + p * 16;
        int r4 = (t & 15) * 4;
        float f0 = T[r4][c], f1 = T[r4 + 1][c], f2 = T[r4 + 2][c], f3 = T[r4 + 3][c];
        ushort4 h, l;
        h.x = f2bf(f0); l.x = f2bf(f0 - bf2f(h.x));
        h.y = f2bf(f1); l.y = f2bf(f1 - bf2f(h.y));
        h.z = f2bf(f2); l.z = f2bf(f2 - bf2f(h.z));
        h.w = f2bf(f3); l.w = f2bf(f3 - bf2f(h.w));
        *(ushort4*)&oh[(size_t)(c0 + c) * R + r0 + r4] = h;
        *(ushort4*)&ol[(size_t)(c0 + c) * R + r0 + r4] = l;
    }
}

// ===========================================================================
// transpose_v: qkv_hi [2048][6144] cols 4096.. (= V bf16) -> vt [2048][2048]
// ===========================================================================
__global__ __launch_bounds__(256)
void transpose_v(const ushort* __restrict__ qkvh, ushort* __restrict__ vt)
{
    __shared__ ushort T[64][72];
    const int t = threadIdx.x;
    const int c0 = blockIdx.x * 64, n0 = blockIdx.y * 64;
    #pragma unroll
    for (int p = 0; p < 2; ++p) {
        int r = (t >> 3) + p * 32;
        int u = (t & 7) * 8;
        *(bf16x8*)&T[r][u] = *(const bf16x8*)&qkvh[(size_t)(n0 + r) * QKV_LD + 2 * DMODEL + c0 + u];
    }
    __syncthreads();
    #pragma unroll
    for (int p = 0; p < 2; ++p) {
        int d = (t >> 3) + p * 32;
        int ju = (t & 7) * 8;
        bf16x8 o;
        #pragma unroll
        for (int i = 0; i < 8; ++i) o[i] = (short)T[ju + i][d];
        *(bf16x8*)&vt[(size_t)(c0 + d) * N_SEQ + n0 + ju] = o;
    }
}

// ===========================================================================
// gemm_v4<BM,BN>: bf16x3 GEMM, C[M][N] = (Ah+Al)[M][K] @ (Bh+Bl)^T (B: [N][K]).
// - v1's coalesced staging (4 lanes = 64B contiguous per row), natural block
//   order (no XCD swizzle: L3-fit regime, swizzle measured -34%/FETCH x2.8).
// - pitch-68 LDS rows [hi 32 | lo 32 | pad 4] -> conflict-free b128 reads.
// - single raw barrier per K-step (lgkmcnt only; no vmcnt(0) drain).
// - depth-2 register pipeline: global loads issued 2 K-steps ahead.
// GEMM1: <128,128> grid 768 (2/CU). GEMM3: <64,128> grid 512 (2/CU).
// ===========================================================================
template<int BM, int BN, bool BF16OUT>
__global__ __launch_bounds__(256, 2)
void gemm_v4(const ushort* __restrict__ Ah_g, const ushort* __restrict__ Al_g,
             const ushort* __restrict__ Bh_g, const ushort* __restrict__ Bl_g,
             ushort* __restrict__ Ch, ushort* __restrict__ Cl,
             float* __restrict__ Cf, int M, int N, int K)
{
    constexpr int GA = BM / 64, GB = BN / 64;
    constexpr int MF = BM / 32, NF = BN / 32;
    __shared__ ushort bufA[2][BM * 68];
    __shared__ ushort bufB[2][BN * 68];

    const int t = threadIdx.x;
    const int l15 = t & 15, kgr = (t >> 4) & 3;
    const int w = t >> 6;
    const int wm = (w >> 1) * (BM / 2), wn = (w & 1) * (BN / 2);
    const int bm = blockIdx.y * BM, bn = blockIdx.x * BN;
    const int sr = t >> 2, sku = (t & 3) * 8;   // 4 lanes cover 64B of one row

    const ushort* pAh = Ah_g + (size_t)(bm + sr) * K + sku;
    const ushort* pAl = Al_g + (size_t)(bm + sr) * K + sku;
    const ushort* pBh = Bh_g + (size_t)(bn + sr) * K + sku;
    const ushort* pBl = Bl_g + (size_t)(bn + sr) * K + sku;

    bf16x8 sA0[2 * GA], sB0[2 * GB], sA1[2 * GA], sB1[2 * GB];
    f32x4 acc[MF][NF] = {};
    const int nt = K / 32;

#define G_LOAD(SA, SB, k0) do { \
    _Pragma("unroll") for (int g = 0; g < GA; ++g) { \
        SA[2*g]   = *(const bf16x8*)(pAh + (size_t)(64*g) * K + (k0)); \
        SA[2*g+1] = *(const bf16x8*)(pAl + (size_t)(64*g) * K + (k0)); } \
    _Pragma("unroll") for (int g = 0; g < GB; ++g) { \
        SB[2*g]   = *(const bf16x8*)(pBh + (size_t)(64*g) * K + (k0)); \
        SB[2*g+1] = *(const bf16x8*)(pBl + (size_t)(64*g) * K + (k0)); } \
} while (0)

#define L_WRITE(SA, SB, c) do { \
    _Pragma("unroll") for (int g = 0; g < GA; ++g) { \
        *(bf16x8*)&bufA[c][(sr + 64*g) * 68 + sku]      = SA[2*g]; \
        *(bf16x8*)&bufA[c][(sr + 64*g) * 68 + 32 + sku] = SA[2*g+1]; } \
    _Pragma("unroll") for (int g = 0; g < GB; ++g) { \
        *(bf16x8*)&bufB[c][(sr + 64*g) * 68 + sku]      = SB[2*g]; \
        *(bf16x8*)&bufB[c][(sr + 64*g) * 68 + 32 + sku] = SB[2*g+1]; } \
} while (0)

#define K_STEP(I, SA, SB, c) do { \
    asm volatile("s_waitcnt lgkmcnt(0)\n\ts_barrier" ::: "memory"); \
    if ((I) + 1 < nt) L_WRITE(SA, SB, (c) ^ 1); \
    if ((I) + 3 < nt) G_LOAD(SA, SB, ((I) + 3) * 32); \
    bf16x8 bh[NF], bl[NF]; \
    _Pragma("unroll") for (int nf = 0; nf < NF; ++nf) { \
        const int r = wn + nf * 16 + l15; \
        bh[nf] = *(const bf16x8*)&bufB[c][r * 68 + kgr * 8]; \
        bl[nf] = *(const bf16x8*)&bufB[c][r * 68 + 32 + kgr * 8]; } \
    _Pragma("unroll") for (int mf = 0; mf < MF; ++mf) { \
        const int r = wm + mf * 16 + l15; \
        bf16x8 ah = *(const bf16x8*)&bufA[c][r * 68 + kgr * 8]; \
        bf16x8 al = *(const bf16x8*)&bufA[c][r * 68 + 32 + kgr * 8]; \
        _Pragma("unroll") for (int nf = 0; nf < NF; ++nf) { \
            acc[mf][nf] = __builtin_amdgcn_mfma_f32_16x16x32_bf16(ah, bh[nf], acc[mf][nf], 0, 0, 0); \
            acc[mf][nf] = __builtin_amdgcn_mfma_f32_16x16x32_bf16(ah, bl[nf], acc[mf][nf], 0, 0, 0); \
            acc[mf][nf] = __builtin_amdgcn_mfma_f32_16x16x32_bf16(al, bh[nf], acc[mf][nf], 0, 0, 0); } } \
} while (0)

    // prologue: step0 -> LDS buf0; step1 -> set1; step2 -> set0 (depth 2)
    G_LOAD(sA0, sB0, 0);
    L_WRITE(sA0, sB0, 0);
    G_LOAD(sA1, sB1, 32);
    G_LOAD(sA0, sB0, 64);

    for (int i = 0; i < nt; i += 2) {
        K_STEP(i,     sA1, sB1, 0);   // writes step i+1 (set1), loads step i+3
        K_STEP(i + 1, sA0, sB0, 1);   // writes step i+2 (set0), loads step i+4
    }

#undef G_LOAD
#undef L_WRITE
#undef K_STEP

    #pragma unroll
    for (int mf = 0; mf < MF; ++mf)
        #pragma unroll
        for (int nf = 0; nf < NF; ++nf)
            #pragma unroll
            for (int r = 0; r < 4; ++r) {
                const int m = bm + wm + mf * 16 + kgr * 4 + r;
                const int n = bn + wn + nf * 16 + l15;
                const float v = acc[mf][nf][r];
                if constexpr (BF16OUT) {
                    ushort h = f2bf(v);
                    Ch[(size_t)m * N + n] = h;
                    Cl[(size_t)m * N + n] = f2bf(v - bf2f(h));
                } else {
                    Cf[(size_t)m * N + n] = v;
                }
            }
}

// ===========================================================================
// attn_mfma2: diagonal-paired flash attention (unchanged — ~33 us measured).
// grid (16, 16) = 256 blocks, 256 thr (4 waves). Block b owns q-strips b and
// 31-b; every wave computes exactly 33 frag-tiles (perfect causal balance).
// ===========================================================================
__global__ __launch_bounds__(256)
void attn_mfma2(const ushort* __restrict__ qkvh, const ushort* __restrict__ qkvl,
                const ushort* __restrict__ vt,
                ushort* __restrict__ oh, ushort* __restrict__ ol)
{
    __shared__ ushort Kh[2][64 * 136], Kl[2][64 * 136];
    __shared__ ushort Vts[2][128 * 68];
    __shared__ ushort St[4][32 * 68];

    const int t = threadIdx.x;
    const int l = t & 63;
    const int w = t >> 6;
    const int l15 = l & 15, kgr = l >> 4;
    const int h = blockIdx.y, b = blockIdx.x;
    const int q00 = b * 64 + w * 16;          // frag0 rows (low strip)
    const int q01 = (31 - b) * 64 + w * 16;   // frag1 rows (high strip)
    const int ntiles = 32 - b;

    bf16x8 qh[2][4], ql[2][4];
    #pragma unroll
    for (int f = 0; f < 2; ++f) {
        const size_t base = (size_t)((f ? q01 : q00) + l15) * QKV_LD + h * HDIM;
        #pragma unroll
        for (int kc = 0; kc < 4; ++kc) {
            qh[f][kc] = *(const bf16x8*)(qkvh + base + kc * 32 + kgr * 8);
            ql[f][kc] = *(const bf16x8*)(qkvl + base + kc * 32 + kgr * 8);
        }
    }

    f32x4 o[2][8] = {};
    float m_run[2][4], l_run[2][4];
    #pragma unroll
    for (int f = 0; f < 2; ++f)
        #pragma unroll
        for (int r = 0; r < 4; ++r) { m_run[f][r] = -1e30f; l_run[f][r] = 0.f; }

    bf16x8 sKh[4], sKl[4], sV[4];
    auto load_tile = [&](int jb) {
        #pragma unroll
        for (int i = 0; i < 4; ++i) {
            int r = (t >> 4) + i * 16;
            size_t g = (size_t)(jb + r) * QKV_LD + DMODEL + h * HDIM + (t & 15) * 8;
            sKh[i] = *(const bf16x8*)(qkvh + g);
            sKl[i] = *(const bf16x8*)(qkvl + g);
        }
        #pragma unroll
        for (int i = 0; i < 4; ++i) {
            int d = (t >> 3) + i * 32;
            sV[i] = *(const bf16x8*)(vt + (size_t)(h * HDIM + d) * N_SEQ + jb + (t & 7) * 8);
        }
    };
    auto write_tile = [&](int c) {
        #pragma unroll
        for (int i = 0; i < 4; ++i) {
            int r = (t >> 4) + i * 16;
            *(bf16x8*)&Kh[c][r * 136 + (t & 15) * 8] = sKh[i];
            *(bf16x8*)&Kl[c][r * 136 + (t & 15) * 8] = sKl[i];
        }
        #pragma unroll
        for (int i = 0; i < 4; ++i) {
            int d = (t >> 3) + i * 32;
            *(bf16x8*)&Vts[c][d * 68 + (t & 7) * 8] = sV[i];
        }
    };

    const float scale = 0.08838834764831845f;  // 1/sqrt(128)

    load_tile(0);
    write_tile(0);
    load_tile(64);

    for (int jt = 0; jt < ntiles; ++jt) {
        const int jb = jt * 64;
        const int c = jt & 1;
        asm volatile("s_waitcnt lgkmcnt(0)\n\ts_barrier" ::: "memory");
        if (jt + 1 < ntiles) write_tile(c ^ 1);
        if (jt + 2 < ntiles) load_tile(jb + 128);

        const bool f0on = (jt <= b);

        float sv[2][4][4];
        #pragma unroll
        for (int jf = 0; jf < 4; ++jf) {
            f32x4 sacc0 = {}, sacc1 = {};
            #pragma unroll
            for (int kc = 0; kc < 4; ++kc) {
                bf16x8 kh = *(const bf16x8*)&Kh[c][(jf * 16 + l15) * 136 + kc * 32 + kgr * 8];
                bf16x8 kl = *(const bf16x8*)&Kl[c][(jf * 16 + l15) * 136 + kc * 32 + kgr * 8];
                sacc1 = __builtin_amdgcn_mfma_f32_16x16x32_bf16(qh[1][kc], kh, sacc1, 0, 0, 0);
                sacc1 = __builtin_amdgcn_mfma_f32_16x16x32_bf16(qh[1][kc], kl, sacc1, 0, 0, 0);
                sacc1 = __builtin_amdgcn_mfma_f32_16x16x32_bf16(ql[1][kc], kh, sacc1, 0, 0, 0);
                if (f0on) {
                    sacc0 = __builtin_amdgcn_mfma_f32_16x16x32_bf16(qh[0][kc], kh, sacc0, 0, 0, 0);
                    sacc0 = __builtin_amdgcn_mfma_f32_16x16x32_bf16(qh[0][kc], kl, sacc0, 0, 0, 0);
                    sacc0 = __builtin_amdgcn_mfma_f32_16x16x32_bf16(ql[0][kc], kh, sacc0, 0, 0, 0);
                }
            }
            const int j = jb + jf * 16 + l15;
            #pragma unroll
            for (int r = 0; r < 4; ++r) {
                sv[1][jf][r] = (j > q01 + kgr * 4 + r) ? -1e30f : sacc1[r] * scale;
                if (f0on)
                    sv[0][jf][r] = (j > q00 + kgr * 4 + r) ? -1e30f : sacc0[r] * scale;
            }
        }

        float corr[2][4];
        #pragma unroll
        for (int f = 0; f < 2; ++f) {
            if (f == 0 && !f0on) continue;
            #pragma unroll
            for (int r = 0; r < 4; ++r) {
                float tm = fmaxf(fmaxf(sv[f][0][r], sv[f][1][r]),
                                 fmaxf(sv[f][2][r], sv[f][3][r]));
                tm = fmaxf(tm, __shfl_xor(tm, 1));
                tm = fmaxf(tm, __shfl_xor(tm, 2));
                tm = fmaxf(tm, __shfl_xor(tm, 4));
                tm = fmaxf(tm, __shfl_xor(tm, 8));
                const float nm = fmaxf(m_run[f][r], tm);
                corr[f][r] = __expf(m_run[f][r] - nm);
                m_run[f][r] = nm;
                float rs = 0.f;
                const int row = f * 16 + kgr * 4 + r;
                #pragma unroll
                for (int jf = 0; jf < 4; ++jf) {
                    const float pv = __expf(sv[f][jf][r] - nm);
                    St[w][row * 68 + jf * 16 + l15] = f2bf(pv);
                    rs += pv;
                }
                rs += __shfl_xor(rs, 1);
                rs += __shfl_xor(rs, 2);
                rs += __shfl_xor(rs, 4);
                rs += __shfl_xor(rs, 8);
                l_run[f][r] = l_run[f][r] * corr[f][r] + rs;
            }
        }

        #pragma unroll
        for (int f = 0; f < 2; ++f) {
            if (f == 0 && !f0on) continue;
            #pragma unroll
            for (int df = 0; df < 8; ++df)
                #pragma unroll
                for (int r = 0; r < 4; ++r) o[f][df][r] *= corr[f][r];
        }

        #pragma unroll
        for (int jc = 0; jc < 2; ++jc) {
            bf16x8 pa1 = *(const bf16x8*)&St[w][(16 + l15) * 68 + jc * 32 + kgr * 8];
            bf16x8 pa0 = {};
            if (f0on) pa0 = *(const bf16x8*)&St[w][l15 * 68 + jc * 32 + kgr * 8];
            #pragma unroll
            for (int df = 0; df < 8; ++df) {
                bf16x8 vb = *(const bf16x8*)&Vts[c][(df * 16 + l15) * 68 + jc * 32 + kgr * 8];
                o[1][df] = __builtin_amdgcn_mfma_f32_16x16x32_bf16(pa1, vb, o[1][df], 0, 0, 0);
                if (f0on)
                    o[0][df] = __builtin_amdgcn_mfma_f32_16x16x32_bf16(pa0, vb, o[0][df], 0, 0, 0);
            }
        }
    }

    #pragma unroll
    for (int f = 0; f < 2; ++f)
        #pragma unroll
        for (int r = 0; r < 4; ++r) l_run[f][r] = 1.f / l_run[f][r];
    #pragma unroll
    for (int f = 0; f < 2; ++f) {
        const int q0 = f ? q01 : q00;
        #pragma unroll
        for (int df = 0; df < 8; ++df)
            #pragma unroll
            for (int r = 0; r < 4; ++r) {
                const float v = o[f][df][r] * l_run[f][r];
                const size_t a = (size_t)(q0 + kgr * 4 + r) * DMODEL + h * HDIM + df * 16 + l15;
                const ushort hh = f2bf(v);
                oh[a] = hh;
                ol[a] = f2bf(v - bf2f(hh));
            }
    }
}

// ===========================================================================
extern "C" void kernel_launch(void* const* d_in, const int* in_sizes, int n_in,
                              void* d_out, int out_size, void* d_ws, size_t ws_size,
                              hipStream_t stream)
{
    const float* x    = (const float*)d_in[0];
    const float* Wqkv = (const float*)d_in[1];
    const float* Wout = (const float*)d_in[2];
    float* outp = (float*)d_out;

    // ws layout (bytes):
    //  [0, 8M)       x_hi   -> later attn_hi
    //  [8M, 16M)     x_lo   -> later attn_lo
    //  [16M, 64M)    wqkvt hi/lo -> later woutt hi/lo + vt
    //  [64M, 112M)   qkv hi/lo
    const size_t O_XHI = 0;
    const size_t O_XLO = 8388608;
    const size_t O_WT  = 16777216;
    const size_t O_QKV = 67108864;

    char* ws = (char*)d_ws;
    ushort* x_hi   = (ushort*)(ws + O_XHI);
    ushort* x_lo   = (ushort*)(ws + O_XLO);
    ushort* wqt_hi = (ushort*)(ws + O_WT);
    ushort* wqt_lo = (ushort*)(ws + O_WT + 25165824);
    ushort* qkv_hi = (ushort*)(ws + O_QKV);
    ushort* qkv_lo = (ushort*)(ws + O_QKV + 25165824);
    ushort* wot_hi = (ushort*)(ws + O_WT);
    ushort* wot_lo = (ushort*)(ws + O_WT + 8388608);
    ushort* vt     = (ushort*)(ws + O_WT + 16777216);
    ushort* at_hi  = (ushort*)(ws + O_XHI);
    ushort* at_lo  = (ushort*)(ws + O_XLO);

    // 1. split x
    convert_split<<<dim3(N_SEQ * DMODEL / 4 / 256), 256, 0, stream>>>(
        x, x_hi, x_lo, N_SEQ * DMODEL / 4);
    // 2. split + transpose Wqkv -> [6144][2048]
    convert_split_t<<<dim3(QKV_LD / 64, DMODEL / 64), 256, 0, stream>>>(
        Wqkv, wqt_hi, wqt_lo, DMODEL, QKV_LD);
    // 3. qkv = x @ Wqkv  (bf16 hi/lo out): 128x128, 768 blocks, 2/CU
    gemm_v4<128, 128, true><<<dim3(QKV_LD / 128, N_SEQ / 128), 256, 0, stream>>>(
        x_hi, x_lo, wqt_hi, wqt_lo, qkv_hi, qkv_lo, nullptr,
        N_SEQ, QKV_LD, DMODEL);
    // 4. split + transpose Wout -> [2048][2048]
    convert_split_t<<<dim3(DMODEL / 64, DMODEL / 64), 256, 0, stream>>>(
        Wout, wot_hi, wot_lo, DMODEL, DMODEL);
    // 5. transpose V (bf16 hi only)
    transpose_v<<<dim3(DMODEL / 64, N_SEQ / 64), 256, 0, stream>>>(qkv_hi, vt);
    // 6. attention (diagonal-paired)
    attn_mfma2<<<dim3(16, NHEAD), 256, 0, stream>>>(
        qkv_hi, qkv_lo, vt, at_hi, at_lo);
    // 7. out = attn @ Wout (fp32 out): 64x128, 512 blocks, 2/CU
    gemm_v4<64, 128, false><<<dim3(DMODEL / 128, N_SEQ / 64), 256, 0, stream>>>(
        at_hi, at_lo, wot_hi, wot_lo, nullptr, nullptr, outp,
        N_SEQ, DMODEL, DMODEL);
}